// Round 6
// baseline (182.358 us; speedup 1.0000x reference)
//
#include <hip/hip_runtime.h>
#include <math.h>

#define D 256
#define S 512
#define M 2048  // 4 * 512

typedef __attribute__((ext_vector_type(8))) short bf16x8;
typedef __attribute__((ext_vector_type(4))) float f32x4;

__device__ inline ushort f2bf(float f) {
    union { float f; unsigned u; } v; v.f = f;
    unsigned r = v.u + 0x7FFFu + ((v.u >> 16) & 1u);   // RNE
    return (ushort)(r >> 16);
}

// ---------------------------------------------------------------------------
// Kernel 0: pack weights to bf16, transposed [n][k] (verified R4).
// ---------------------------------------------------------------------------
__global__ __launch_bounds__(256) void pack_w(
    const float* __restrict__ W1, const float* __restrict__ Wv,
    const float* __restrict__ Wo, ushort* __restrict__ WAt,
    ushort* __restrict__ WBt, ushort* __restrict__ Wvt, ushort* __restrict__ Wot)
{
    const int blk = blockIdx.x, t = threadIdx.x;
    const int mat = blk >> 4;
    const int a0 = ((blk >> 2) & 3) * 64;
    const int b0 = (blk & 3) * 64;
    __shared__ ushort lt[64][72];
    const int r = t >> 4;
    const int c = (t & 15) * 4;
#pragma unroll
    for (int p = 0; p < 4; ++p) {
        const int sr = b0 + p * 16 + r;
        float4 v;
        if (mat == 0) {
            float4 wa = *(const float4*)(W1 + (size_t)sr * 256 + a0 + c);
            float4 wc = *(const float4*)(W1 + (size_t)(512 + sr) * 256 + a0 + c);
            v = make_float4(wa.x + wc.x, wa.y + wc.y, wa.z + wc.z, wa.w + wc.w);
        } else if (mat == 1) {
            float4 wb = *(const float4*)(W1 + (size_t)(256 + sr) * 256 + a0 + c);
            float4 wc = *(const float4*)(W1 + (size_t)(512 + sr) * 256 + a0 + c);
            v = make_float4(wb.x - wc.x, wb.y - wc.y, wb.z - wc.z, wb.w - wc.w);
        } else if (mat == 2) {
            v = *(const float4*)(Wv + (size_t)sr * 256 + a0 + c);
        } else {
            v = *(const float4*)(Wo + (size_t)sr * 256 + a0 + c);
        }
        lt[p * 16 + r][c + 0] = f2bf(v.x);
        lt[p * 16 + r][c + 1] = f2bf(v.y);
        lt[p * 16 + r][c + 2] = f2bf(v.z);
        lt[p * 16 + r][c + 3] = f2bf(v.w);
    }
    __syncthreads();
    ushort* dst = (mat == 0) ? WAt : (mat == 1) ? WBt : (mat == 2) ? Wvt : Wot;
#pragma unroll
    for (int p = 0; p < 4; ++p) {
        const int dr = p * 16 + r;
        ushort4 o = make_ushort4(lt[c + 0][dr], lt[c + 1][dr],
                                 lt[c + 2][dr], lt[c + 3][dr]);
        *(ushort4*)(dst + (size_t)(a0 + dr) * 256 + b0 + c) = o;
    }
}

// ---------------------------------------------------------------------------
// Kernel 1: MFMA QKV (verified R4).  region 0 -> hi (+b1), 1 -> hj,
//   2 -> vals_t bf16 transposed [b][e][j].
// ---------------------------------------------------------------------------
__global__ __launch_bounds__(256) void gemm_qkv_mfma(
    const float* __restrict__ x, const ushort* __restrict__ WAt,
    const ushort* __restrict__ WBt, const ushort* __restrict__ Wvt,
    const float* __restrict__ b1, const float* __restrict__ bv,
    float* __restrict__ hi, float* __restrict__ hj, ushort* __restrict__ vals_t)
{
    const int bn = blockIdx.x, bm = blockIdx.y;
    const int n0 = bn * 64, m0 = bm * 64;
    const int region = n0 >> 8, c0 = n0 & 255;
    const ushort* Bt = (region == 0) ? WAt : (region == 1) ? WBt : Wvt;
    const int t = threadIdx.x, w = t >> 6, l = t & 63;
    const int q = l >> 4, ln = l & 15;
    const int wm = (w >> 1) * 32, wn = (w & 1) * 32;

    __shared__ ushort T[64][72];

    f32x4 acc[2][2] = {};
    for (int k0 = 0; k0 < 256; k0 += 32) {
        union { bf16x8 v; ushort s[8]; } a[2];
        bf16x8 b[2];
#pragma unroll
        for (int mt = 0; mt < 2; ++mt) {
            const float* xr = x + (size_t)(m0 + wm + mt * 16 + ln) * 256 + k0 + q * 8;
            float4 u0 = *(const float4*)xr;
            float4 u1 = *(const float4*)(xr + 4);
            a[mt].s[0] = f2bf(u0.x); a[mt].s[1] = f2bf(u0.y);
            a[mt].s[2] = f2bf(u0.z); a[mt].s[3] = f2bf(u0.w);
            a[mt].s[4] = f2bf(u1.x); a[mt].s[5] = f2bf(u1.y);
            a[mt].s[6] = f2bf(u1.z); a[mt].s[7] = f2bf(u1.w);
        }
#pragma unroll
        for (int nt = 0; nt < 2; ++nt)
            b[nt] = *(const bf16x8*)(Bt + (size_t)(c0 + wn + nt * 16 + ln) * 256 + k0 + q * 8);
#pragma unroll
        for (int mt = 0; mt < 2; ++mt)
#pragma unroll
            for (int nt = 0; nt < 2; ++nt)
                acc[mt][nt] = __builtin_amdgcn_mfma_f32_16x16x32_bf16(a[mt].v, b[nt], acc[mt][nt], 0, 0, 0);
    }

    if (region < 2) {
        float* dst = (region == 0) ? hi : hj;
#pragma unroll
        for (int nt = 0; nt < 2; ++nt) {
            const int col = c0 + wn + nt * 16 + ln;
            const float bias = (region == 0) ? b1[col] : 0.f;
#pragma unroll
            for (int mt = 0; mt < 2; ++mt)
#pragma unroll
                for (int r = 0; r < 4; ++r) {
                    const int row = m0 + wm + mt * 16 + q * 4 + r;
                    dst[(size_t)row * 256 + col] = acc[mt][nt][r] + bias;
                }
        }
    } else {
#pragma unroll
        for (int nt = 0; nt < 2; ++nt) {
            const int cl = wn + nt * 16 + ln;
            const float bias = bv[c0 + cl];
#pragma unroll
            for (int mt = 0; mt < 2; ++mt)
#pragma unroll
                for (int r = 0; r < 4; ++r)
                    T[cl][wm + mt * 16 + q * 4 + r] = f2bf(acc[mt][nt][r] + bias);
        }
        __syncthreads();
        const int bb = m0 >> 9, jloc = m0 & 511;
#pragma unroll
        for (int p = 0; p < 2; ++p) {
            const int idx = p * 256 + t;
            const int e_l = idx & 63, jc = (idx >> 6) * 8;
            *(uint4*)(vals_t + ((size_t)(bb * 256 + c0 + e_l)) * 512 + jloc + jc) =
                *(const uint4*)&T[e_l][jc];
        }
    }
}

// ---------------------------------------------------------------------------
// Kernel 2: scores, 64i x 32j tiles (verified R4).
// ---------------------------------------------------------------------------
__global__ __launch_bounds__(256) void scores64(
    const float* __restrict__ hi, const float* __restrict__ hj,
    const float* __restrict__ w2, float* __restrict__ sc)
{
    const int jt = blockIdx.x, it = blockIdx.y, bb = blockIdx.z;
    if (jt > 2 * it + 1) return;
    const int i0 = it * 64, j0 = jt * 32;
    const int t = threadIdx.x, w = t >> 6, l = t & 63;
    const int q = l >> 4, ln = l & 15;

    __shared__ __align__(16) float His[32][64];
    __shared__ __align__(16) float Sst[64][36];
    __shared__ float w2s[256];
    if (t < 64) *(float4*)&w2s[t * 4] = *(const float4*)(w2 + t * 4);

    const int si = t & 63, sh = (t >> 6) * 8;
    const float* hisrc = hi + (size_t)((bb << 9) + i0 + si) * 256 + sh;
    const int jrow = w * 8 + q * 2;
    const float* hj0 = hj + (size_t)((bb << 9) + j0 + jrow) * 256;
    const float* hj1 = hj0 + 256;

    float acc00 = 0.f, acc01 = 0.f, acc10 = 0.f, acc11 = 0.f;
    float acc20 = 0.f, acc21 = 0.f, acc30 = 0.f, acc31 = 0.f;

    for (int hc = 0; hc < 256; hc += 32) {
        float4 a0 = *(const float4*)(hisrc + hc);
        float4 a1 = *(const float4*)(hisrc + hc + 4);
        float e0[32], e1[32];
#pragma unroll
        for (int c = 0; c < 8; ++c) {
            *(float4*)&e0[c * 4] = *(const float4*)(hj0 + hc + c * 4);
            *(float4*)&e1[c * 4] = *(const float4*)(hj1 + hc + c * 4);
        }
        __syncthreads();
        His[sh + 0][si] = a0.x; His[sh + 1][si] = a0.y;
        His[sh + 2][si] = a0.z; His[sh + 3][si] = a0.w;
        His[sh + 4][si] = a1.x; His[sh + 5][si] = a1.y;
        His[sh + 6][si] = a1.z; His[sh + 7][si] = a1.w;
        __syncthreads();
#pragma unroll
        for (int h = 0; h < 32; ++h) {
            float4 a = *(const float4*)&His[h][ln * 4];
            const float wv = w2s[hc + h];
            const float f0 = e0[h], f1 = e1[h];
            acc00 += fmaxf(a.x + f0, 0.f) * wv;
            acc01 += fmaxf(a.x + f1, 0.f) * wv;
            acc10 += fmaxf(a.y + f0, 0.f) * wv;
            acc11 += fmaxf(a.y + f1, 0.f) * wv;
            acc20 += fmaxf(a.z + f0, 0.f) * wv;
            acc21 += fmaxf(a.z + f1, 0.f) * wv;
            acc30 += fmaxf(a.w + f0, 0.f) * wv;
            acc31 += fmaxf(a.w + f1, 0.f) * wv;
        }
    }

    Sst[ln * 4 + 0][jrow] = acc00;  Sst[ln * 4 + 0][jrow + 1] = acc01;
    Sst[ln * 4 + 1][jrow] = acc10;  Sst[ln * 4 + 1][jrow + 1] = acc11;
    Sst[ln * 4 + 2][jrow] = acc20;  Sst[ln * 4 + 2][jrow + 1] = acc21;
    Sst[ln * 4 + 3][jrow] = acc30;  Sst[ln * 4 + 3][jrow + 1] = acc31;
    __syncthreads();
    const int i_l = t >> 2, jc = (t & 3) * 8;
    float* dst = sc + ((size_t)bb << 18) + (size_t)(i0 + i_l) * 512 + j0 + jc;
    *(float4*)dst       = *(const float4*)&Sst[i_l][jc];
    *(float4*)(dst + 4) = *(const float4*)&Sst[i_l][jc + 4];
}

// ---------------------------------------------------------------------------
// Kernel 3: FUSED softmax + PV (MFMA).  Grid (4 n-tiles, 8 m-tiles, 4 b) =
//   128 blocks — same parallelism as R4's pv.  Each block softmaxes its own
//   64 rows from sc into LDS as UNNORMALIZED e=exp(s-m) bf16 (normalization
//   commutes with PV; applied as 1/sum in the epilogue).  Row 0: inv=0.
// ---------------------------------------------------------------------------
__global__ __launch_bounds__(256) void pv_sm(
    const float* __restrict__ sc, const ushort* __restrict__ vals_t,
    ushort* __restrict__ msg_bf)
{
    const int bn = blockIdx.x, bm = blockIdx.y, b = blockIdx.z;
    const int n0 = bn * 64, m0 = bm * 64;
    const int kmax = m0 + 64;            // causal: row i needs j < i <= kmax
    const int t = threadIdx.x, w = t >> 6, l = t & 63;
    const int q = l >> 4, ln = l & 15;
    const int wm = (w >> 1) * 32, wn = (w & 1) * 32;

    __shared__ ushort P[64][520];        // unnormalized exp, bf16
    __shared__ float invS[64];

    const float* scb = sc + ((size_t)b << 18);
    // ---- softmax: wave w handles rows w*16 .. w*16+15 ----
    for (int rr = 0; rr < 16; ++rr) {
        const int r = w * 16 + rr;
        const int i = m0 + r;
        for (int j = l; j < kmax; j += 64) P[r][j] = 0;
        if (i == 0) { if (l == 0) invS[r] = 0.f; continue; }
        const float* srow = scb + (size_t)i * S;
        float mx = -3.0e38f;
        for (int j = l; j < i; j += 64) mx = fmaxf(mx, srow[j]);
#pragma unroll
        for (int off = 32; off; off >>= 1) mx = fmaxf(mx, __shfl_xor(mx, off, 64));
        float s = 0.f;
        for (int j = l; j < i; j += 64) {
            float e = __expf(srow[j] - mx);
            P[r][j] = f2bf(e);
            s += e;
        }
#pragma unroll
        for (int off = 32; off; off >>= 1) s += __shfl_xor(s, off, 64);
        if (l == 0) invS[r] = 1.f / s;
    }
    __syncthreads();

    // ---- PV: wave tile 32x32 within 64x64 block tile ----
    const ushort* V = vals_t + (size_t)(b * 256) * 512;
    f32x4 acc[2][2] = {};
    for (int k0 = 0; k0 < kmax; k0 += 32) {
        bf16x8 a[2], bb[2];
#pragma unroll
        for (int mt = 0; mt < 2; ++mt)
            a[mt] = *(const bf16x8*)&P[wm + mt * 16 + ln][k0 + q * 8];
#pragma unroll
        for (int nt = 0; nt < 2; ++nt)
            bb[nt] = *(const bf16x8*)(V + (size_t)(n0 + wn + nt * 16 + ln) * 512 + k0 + q * 8);
#pragma unroll
        for (int mt = 0; mt < 2; ++mt)
#pragma unroll
            for (int nt = 0; nt < 2; ++nt)
                acc[mt][nt] = __builtin_amdgcn_mfma_f32_16x16x32_bf16(a[mt], bb[nt], acc[mt][nt], 0, 0, 0);
    }
#pragma unroll
    for (int nt = 0; nt < 2; ++nt) {
        const int col = n0 + wn + nt * 16 + ln;
#pragma unroll
        for (int mt = 0; mt < 2; ++mt)
#pragma unroll
            for (int r = 0; r < 4; ++r) {
                const int rl = wm + mt * 16 + q * 4 + r;
                const int row = (b << 9) + m0 + rl;
                msg_bf[(size_t)row * 256 + col] = f2bf(acc[mt][nt][r] * invS[rl]);
            }
    }
}

// ---------------------------------------------------------------------------
// Kernel 4: MFMA OUT + residual + bias + LayerNorm (verified R4). 128 blocks.
// ---------------------------------------------------------------------------
__global__ __launch_bounds__(256) void out_ln_mfma(
    const ushort* __restrict__ msg_bf, const ushort* __restrict__ Wot,
    const float* __restrict__ x, const float* __restrict__ bo,
    const float* __restrict__ gamma, const float* __restrict__ beta,
    float* __restrict__ out)
{
    const int r0 = blockIdx.x * 16;
    const int t = threadIdx.x, w = t >> 6, l = t & 63;
    const int q = l >> 4, ln = l & 15;

    __shared__ float redS[16][4], redQ[16][4];

    f32x4 acc[4] = {};
    for (int k0 = 0; k0 < 256; k0 += 32) {
        bf16x8 a = *(const bf16x8*)(msg_bf + (size_t)(r0 + ln) * 256 + k0 + q * 8);
#pragma unroll
        for (int nt = 0; nt < 4; ++nt) {
            bf16x8 bb = *(const bf16x8*)(Wot + (size_t)(w * 64 + nt * 16 + ln) * 256 + k0 + q * 8);
            acc[nt] = __builtin_amdgcn_mfma_f32_16x16x32_bf16(a, bb, acc[nt], 0, 0, 0);
        }
    }

    float sum[4] = {}, sq[4] = {};
#pragma unroll
    for (int nt = 0; nt < 4; ++nt) {
        const int col = w * 64 + nt * 16 + ln;
        const float bov = bo[col];
#pragma unroll
        for (int r = 0; r < 4; ++r) {
            const int row = r0 + q * 4 + r;
            float v = acc[nt][r] + x[(size_t)row * 256 + col] + bov;
            acc[nt][r] = v;
            sum[r] += v;
            sq[r] += v * v;
        }
    }
#pragma unroll
    for (int r = 0; r < 4; ++r) {
#pragma unroll
        for (int off = 1; off < 16; off <<= 1) {
            sum[r] += __shfl_xor(sum[r], off, 64);
            sq[r]  += __shfl_xor(sq[r],  off, 64);
        }
    }
    if (ln == 0) {
#pragma unroll
        for (int r = 0; r < 4; ++r) {
            redS[q * 4 + r][w] = sum[r];
            redQ[q * 4 + r][w] = sq[r];
        }
    }
    __syncthreads();
#pragma unroll
    for (int nt = 0; nt < 4; ++nt) {
        const int col = w * 64 + nt * 16 + ln;
        const float g = gamma[col], be = beta[col];
#pragma unroll
        for (int r = 0; r < 4; ++r) {
            const int rl = q * 4 + r;
            const float ts = redS[rl][0] + redS[rl][1] + redS[rl][2] + redS[rl][3];
            const float tq = redQ[rl][0] + redQ[rl][1] + redQ[rl][2] + redQ[rl][3];
            const float mu = ts * (1.f / 256.f);
            const float var = tq * (1.f / 256.f) - mu * mu;
            out[(size_t)(r0 + rl) * 256 + col] =
                (acc[nt][r] - mu) * rsqrtf(var + 1e-5f) * g + be;
        }
    }
}

// ---------------------------------------------------------------------------
extern "C" void kernel_launch(void* const* d_in, const int* in_sizes, int n_in,
                              void* d_out, int out_size, void* d_ws, size_t ws_size,
                              hipStream_t stream)
{
    (void)in_sizes; (void)n_in; (void)out_size; (void)ws_size;
    const float* x     = (const float*)d_in[0];
    const float* W1    = (const float*)d_in[1];
    const float* b1    = (const float*)d_in[2];
    const float* w2    = (const float*)d_in[3];
    const float* Wv    = (const float*)d_in[5];
    const float* bv    = (const float*)d_in[6];
    const float* Wo    = (const float*)d_in[7];
    const float* bo    = (const float*)d_in[8];
    const float* gamma = (const float*)d_in[9];
    const float* beta  = (const float*)d_in[10];
    float* out = (float*)d_out;

    // workspace layout in 256KB (64K-float) chunks
    float* ws = (float*)d_ws;
    const size_t CH = 64 * 1024;
    float*  hi      = ws;                       // 8 chunks (2048*256 f32)
    float*  hj      = ws + 8 * CH;              // 8
    float*  sc      = ws + 16 * CH;             // 16 (4*512*512 f32)
    ushort* WAt     = (ushort*)(ws + 32 * CH);  // 1
    ushort* WBt     = (ushort*)(ws + 33 * CH);  // 1
    ushort* Wvt     = (ushort*)(ws + 34 * CH);  // 1
    ushort* Wot     = (ushort*)(ws + 35 * CH);  // 1
    ushort* vals_t  = (ushort*)(ws + 36 * CH);  // 4  (4*256*512 bf16, [b][e][j])
    ushort* msg_bf  = (ushort*)(ws + 40 * CH);  // 4  (2048*256 bf16)

    pack_w       <<<dim3(64),        256, 0, stream>>>(W1, Wv, Wo, WAt, WBt, Wvt, Wot);
    gemm_qkv_mfma<<<dim3(12, 32),    256, 0, stream>>>(x, WAt, WBt, Wvt, b1, bv, hi, hj, vals_t);
    scores64     <<<dim3(16, 8, 4),  256, 0, stream>>>(hi, hj, w2, sc);
    pv_sm        <<<dim3(4, 8, 4),   256, 0, stream>>>(sc, vals_t, msg_bf);
    out_ln_mfma  <<<dim3(128),       256, 0, stream>>>(msg_bf, Wot, x, bo, gamma, beta, out);
}

// Round 7
// 141.335 us; speedup vs baseline: 1.2903x; 1.2903x over previous
//
#include <hip/hip_runtime.h>
#include <math.h>

#define D 256
#define S 512
#define M 2048  // 4 * 512

typedef __attribute__((ext_vector_type(8))) short bf16x8;
typedef __attribute__((ext_vector_type(4))) float f32x4;

__device__ inline ushort f2bf(float f) {
    union { float f; unsigned u; } v; v.f = f;
    unsigned r = v.u + 0x7FFFu + ((v.u >> 16) & 1u);   // RNE
    return (ushort)(r >> 16);
}

// ---------------------------------------------------------------------------
// Kernel 0: pack weights to bf16, transposed [n][k] (verified R4).
// ---------------------------------------------------------------------------
__global__ __launch_bounds__(256) void pack_w(
    const float* __restrict__ W1, const float* __restrict__ Wv,
    const float* __restrict__ Wo, ushort* __restrict__ WAt,
    ushort* __restrict__ WBt, ushort* __restrict__ Wvt, ushort* __restrict__ Wot)
{
    const int blk = blockIdx.x, t = threadIdx.x;
    const int mat = blk >> 4;
    const int a0 = ((blk >> 2) & 3) * 64;
    const int b0 = (blk & 3) * 64;
    __shared__ ushort lt[64][72];
    const int r = t >> 4;
    const int c = (t & 15) * 4;
#pragma unroll
    for (int p = 0; p < 4; ++p) {
        const int sr = b0 + p * 16 + r;
        float4 v;
        if (mat == 0) {
            float4 wa = *(const float4*)(W1 + (size_t)sr * 256 + a0 + c);
            float4 wc = *(const float4*)(W1 + (size_t)(512 + sr) * 256 + a0 + c);
            v = make_float4(wa.x + wc.x, wa.y + wc.y, wa.z + wc.z, wa.w + wc.w);
        } else if (mat == 1) {
            float4 wb = *(const float4*)(W1 + (size_t)(256 + sr) * 256 + a0 + c);
            float4 wc = *(const float4*)(W1 + (size_t)(512 + sr) * 256 + a0 + c);
            v = make_float4(wb.x - wc.x, wb.y - wc.y, wb.z - wc.z, wb.w - wc.w);
        } else if (mat == 2) {
            v = *(const float4*)(Wv + (size_t)sr * 256 + a0 + c);
        } else {
            v = *(const float4*)(Wo + (size_t)sr * 256 + a0 + c);
        }
        lt[p * 16 + r][c + 0] = f2bf(v.x);
        lt[p * 16 + r][c + 1] = f2bf(v.y);
        lt[p * 16 + r][c + 2] = f2bf(v.z);
        lt[p * 16 + r][c + 3] = f2bf(v.w);
    }
    __syncthreads();
    ushort* dst = (mat == 0) ? WAt : (mat == 1) ? WBt : (mat == 2) ? Wvt : Wot;
#pragma unroll
    for (int p = 0; p < 4; ++p) {
        const int dr = p * 16 + r;
        ushort4 o = make_ushort4(lt[c + 0][dr], lt[c + 1][dr],
                                 lt[c + 2][dr], lt[c + 3][dr]);
        *(ushort4*)(dst + (size_t)(a0 + dr) * 256 + b0 + c) = o;
    }
}

// ---------------------------------------------------------------------------
// Kernel 1: MFMA QKV (verified R4).  region 0 -> hi (+b1), 1 -> hj,
//   2 -> vals_t bf16 transposed [b][e][j].
// ---------------------------------------------------------------------------
__global__ __launch_bounds__(256) void gemm_qkv_mfma(
    const float* __restrict__ x, const ushort* __restrict__ WAt,
    const ushort* __restrict__ WBt, const ushort* __restrict__ Wvt,
    const float* __restrict__ b1, const float* __restrict__ bv,
    float* __restrict__ hi, float* __restrict__ hj, ushort* __restrict__ vals_t)
{
    const int bn = blockIdx.x, bm = blockIdx.y;
    const int n0 = bn * 64, m0 = bm * 64;
    const int region = n0 >> 8, c0 = n0 & 255;
    const ushort* Bt = (region == 0) ? WAt : (region == 1) ? WBt : Wvt;
    const int t = threadIdx.x, w = t >> 6, l = t & 63;
    const int q = l >> 4, ln = l & 15;
    const int wm = (w >> 1) * 32, wn = (w & 1) * 32;

    __shared__ ushort T[64][72];

    f32x4 acc[2][2] = {};
    for (int k0 = 0; k0 < 256; k0 += 32) {
        union { bf16x8 v; ushort s[8]; } a[2];
        bf16x8 b[2];
#pragma unroll
        for (int mt = 0; mt < 2; ++mt) {
            const float* xr = x + (size_t)(m0 + wm + mt * 16 + ln) * 256 + k0 + q * 8;
            float4 u0 = *(const float4*)xr;
            float4 u1 = *(const float4*)(xr + 4);
            a[mt].s[0] = f2bf(u0.x); a[mt].s[1] = f2bf(u0.y);
            a[mt].s[2] = f2bf(u0.z); a[mt].s[3] = f2bf(u0.w);
            a[mt].s[4] = f2bf(u1.x); a[mt].s[5] = f2bf(u1.y);
            a[mt].s[6] = f2bf(u1.z); a[mt].s[7] = f2bf(u1.w);
        }
#pragma unroll
        for (int nt = 0; nt < 2; ++nt)
            b[nt] = *(const bf16x8*)(Bt + (size_t)(c0 + wn + nt * 16 + ln) * 256 + k0 + q * 8);
#pragma unroll
        for (int mt = 0; mt < 2; ++mt)
#pragma unroll
            for (int nt = 0; nt < 2; ++nt)
                acc[mt][nt] = __builtin_amdgcn_mfma_f32_16x16x32_bf16(a[mt].v, b[nt], acc[mt][nt], 0, 0, 0);
    }

    if (region < 2) {
        float* dst = (region == 0) ? hi : hj;
#pragma unroll
        for (int nt = 0; nt < 2; ++nt) {
            const int col = c0 + wn + nt * 16 + ln;
            const float bias = (region == 0) ? b1[col] : 0.f;
#pragma unroll
            for (int mt = 0; mt < 2; ++mt)
#pragma unroll
                for (int r = 0; r < 4; ++r) {
                    const int row = m0 + wm + mt * 16 + q * 4 + r;
                    dst[(size_t)row * 256 + col] = acc[mt][nt][r] + bias;
                }
        }
    } else {
#pragma unroll
        for (int nt = 0; nt < 2; ++nt) {
            const int cl = wn + nt * 16 + ln;
            const float bias = bv[c0 + cl];
#pragma unroll
            for (int mt = 0; mt < 2; ++mt)
#pragma unroll
                for (int r = 0; r < 4; ++r)
                    T[cl][wm + mt * 16 + q * 4 + r] = f2bf(acc[mt][nt][r] + bias);
        }
        __syncthreads();
        const int bb = m0 >> 9, jloc = m0 & 511;
#pragma unroll
        for (int p = 0; p < 2; ++p) {
            const int idx = p * 256 + t;
            const int e_l = idx & 63, jc = (idx >> 6) * 8;
            *(uint4*)(vals_t + ((size_t)(bb * 256 + c0 + e_l)) * 512 + jloc + jc) =
                *(const uint4*)&T[e_l][jc];
        }
    }
}

// ---------------------------------------------------------------------------
// Kernel 2: scores, 64i x 32j tiles (verified R4).
// ---------------------------------------------------------------------------
__global__ __launch_bounds__(256) void scores64(
    const float* __restrict__ hi, const float* __restrict__ hj,
    const float* __restrict__ w2, float* __restrict__ sc)
{
    const int jt = blockIdx.x, it = blockIdx.y, bb = blockIdx.z;
    if (jt > 2 * it + 1) return;
    const int i0 = it * 64, j0 = jt * 32;
    const int t = threadIdx.x, w = t >> 6, l = t & 63;
    const int q = l >> 4, ln = l & 15;

    __shared__ __align__(16) float His[32][64];
    __shared__ __align__(16) float Sst[64][36];
    __shared__ float w2s[256];
    if (t < 64) *(float4*)&w2s[t * 4] = *(const float4*)(w2 + t * 4);

    const int si = t & 63, sh = (t >> 6) * 8;
    const float* hisrc = hi + (size_t)((bb << 9) + i0 + si) * 256 + sh;
    const int jrow = w * 8 + q * 2;
    const float* hj0 = hj + (size_t)((bb << 9) + j0 + jrow) * 256;
    const float* hj1 = hj0 + 256;

    float acc00 = 0.f, acc01 = 0.f, acc10 = 0.f, acc11 = 0.f;
    float acc20 = 0.f, acc21 = 0.f, acc30 = 0.f, acc31 = 0.f;

    for (int hc = 0; hc < 256; hc += 32) {
        float4 a0 = *(const float4*)(hisrc + hc);
        float4 a1 = *(const float4*)(hisrc + hc + 4);
        float e0[32], e1[32];
#pragma unroll
        for (int c = 0; c < 8; ++c) {
            *(float4*)&e0[c * 4] = *(const float4*)(hj0 + hc + c * 4);
            *(float4*)&e1[c * 4] = *(const float4*)(hj1 + hc + c * 4);
        }
        __syncthreads();
        His[sh + 0][si] = a0.x; His[sh + 1][si] = a0.y;
        His[sh + 2][si] = a0.z; His[sh + 3][si] = a0.w;
        His[sh + 4][si] = a1.x; His[sh + 5][si] = a1.y;
        His[sh + 6][si] = a1.z; His[sh + 7][si] = a1.w;
        __syncthreads();
#pragma unroll
        for (int h = 0; h < 32; ++h) {
            float4 a = *(const float4*)&His[h][ln * 4];
            const float wv = w2s[hc + h];
            const float f0 = e0[h], f1 = e1[h];
            acc00 += fmaxf(a.x + f0, 0.f) * wv;
            acc01 += fmaxf(a.x + f1, 0.f) * wv;
            acc10 += fmaxf(a.y + f0, 0.f) * wv;
            acc11 += fmaxf(a.y + f1, 0.f) * wv;
            acc20 += fmaxf(a.z + f0, 0.f) * wv;
            acc21 += fmaxf(a.z + f1, 0.f) * wv;
            acc30 += fmaxf(a.w + f0, 0.f) * wv;
            acc31 += fmaxf(a.w + f1, 0.f) * wv;
        }
    }

    Sst[ln * 4 + 0][jrow] = acc00;  Sst[ln * 4 + 0][jrow + 1] = acc01;
    Sst[ln * 4 + 1][jrow] = acc10;  Sst[ln * 4 + 1][jrow + 1] = acc11;
    Sst[ln * 4 + 2][jrow] = acc20;  Sst[ln * 4 + 2][jrow + 1] = acc21;
    Sst[ln * 4 + 3][jrow] = acc30;  Sst[ln * 4 + 3][jrow + 1] = acc31;
    __syncthreads();
    const int i_l = t >> 2, jc = (t & 3) * 8;
    float* dst = sc + ((size_t)bb << 18) + (size_t)(i0 + i_l) * 512 + j0 + jc;
    *(float4*)dst       = *(const float4*)&Sst[i_l][jc];
    *(float4*)(dst + 4) = *(const float4*)&Sst[i_l][jc + 4];
}

// ---------------------------------------------------------------------------
// Kernel 3: softmax -> attn_bf, REGISTER-RESIDENT (2 elements/thread).
//   One block per row; no LDS score array, single global read + single exp.
// ---------------------------------------------------------------------------
__global__ __launch_bounds__(256) void attn_norm(
    const float* __restrict__ sc, ushort* __restrict__ attn_bf)
{
    const int row = blockIdx.x;
    const int b = row >> 9, i = row & 511;
    const int t = threadIdx.x, wave = t >> 6, lane = t & 63;
    ushort* arow = attn_bf + ((size_t)(b << 9) + i) * S;

    if (i == 0) { arow[t] = 0; arow[t + 256] = 0; return; }

    const float* srow = sc + ((size_t)b << 18) + (size_t)i * S;
    __shared__ float red[8];

    const float v0 = (t < i)       ? srow[t]       : -3.0e38f;
    const float v1 = (t + 256 < i) ? srow[t + 256] : -3.0e38f;

    float m = fmaxf(v0, v1);
#pragma unroll
    for (int off = 32; off; off >>= 1) m = fmaxf(m, __shfl_xor(m, off, 64));
    if (lane == 0) red[wave] = m;
    __syncthreads();
    const float mx = fmaxf(fmaxf(red[0], red[1]), fmaxf(red[2], red[3]));

    const float e0 = (t < i)       ? __expf(v0 - mx) : 0.f;
    const float e1 = (t + 256 < i) ? __expf(v1 - mx) : 0.f;
    float s = e0 + e1;
#pragma unroll
    for (int off = 32; off; off >>= 1) s += __shfl_xor(s, off, 64);
    if (lane == 0) red[4 + wave] = s;
    __syncthreads();
    const float inv = 1.f / (red[4] + red[5] + red[6] + red[7]);

    arow[t]       = f2bf(e0 * inv);
    arow[t + 256] = f2bf(e1 * inv);
}

// ---------------------------------------------------------------------------
// Kernel 4: MFMA PV (verified R4).  msg = attn @ vals, causal K-truncation.
// ---------------------------------------------------------------------------
__global__ __launch_bounds__(256) void pv_mfma(
    const ushort* __restrict__ attn_bf, const ushort* __restrict__ vals_t,
    ushort* __restrict__ msg_bf)
{
    const int bn = blockIdx.x, bm = blockIdx.y, b = blockIdx.z;
    const int n0 = bn * 64, m0 = bm * 64;
    const ushort* A = attn_bf + ((size_t)b << 18);
    const ushort* V = vals_t + (size_t)(b * 256) * 512;
    const int t = threadIdx.x, w = t >> 6, l = t & 63;
    const int q = l >> 4, ln = l & 15;
    const int wm = (w >> 1) * 32, wn = (w & 1) * 32;

    f32x4 acc[2][2] = {};
    const int kmax = m0 + 64;
    for (int k0 = 0; k0 < kmax; k0 += 32) {
        bf16x8 a[2], bb[2];
#pragma unroll
        for (int mt = 0; mt < 2; ++mt)
            a[mt] = *(const bf16x8*)(A + (size_t)(m0 + wm + mt * 16 + ln) * S + k0 + q * 8);
#pragma unroll
        for (int nt = 0; nt < 2; ++nt)
            bb[nt] = *(const bf16x8*)(V + (size_t)(n0 + wn + nt * 16 + ln) * 512 + k0 + q * 8);
#pragma unroll
        for (int mt = 0; mt < 2; ++mt)
#pragma unroll
            for (int nt = 0; nt < 2; ++nt)
                acc[mt][nt] = __builtin_amdgcn_mfma_f32_16x16x32_bf16(a[mt], bb[nt], acc[mt][nt], 0, 0, 0);
    }
#pragma unroll
    for (int nt = 0; nt < 2; ++nt) {
        const int col = n0 + wn + nt * 16 + ln;
#pragma unroll
        for (int mt = 0; mt < 2; ++mt)
#pragma unroll
            for (int r = 0; r < 4; ++r) {
                const int row = (b << 9) + m0 + wm + mt * 16 + q * 4 + r;
                msg_bf[(size_t)row * 256 + col] = f2bf(acc[mt][nt][r]);
            }
    }
}

// ---------------------------------------------------------------------------
// Kernel 5: MFMA OUT + residual + bias + LayerNorm (verified R4). 128 blocks.
// ---------------------------------------------------------------------------
__global__ __launch_bounds__(256) void out_ln_mfma(
    const ushort* __restrict__ msg_bf, const ushort* __restrict__ Wot,
    const float* __restrict__ x, const float* __restrict__ bo,
    const float* __restrict__ gamma, const float* __restrict__ beta,
    float* __restrict__ out)
{
    const int r0 = blockIdx.x * 16;
    const int t = threadIdx.x, w = t >> 6, l = t & 63;
    const int q = l >> 4, ln = l & 15;

    __shared__ float redS[16][4], redQ[16][4];

    f32x4 acc[4] = {};
    for (int k0 = 0; k0 < 256; k0 += 32) {
        bf16x8 a = *(const bf16x8*)(msg_bf + (size_t)(r0 + ln) * 256 + k0 + q * 8);
#pragma unroll
        for (int nt = 0; nt < 4; ++nt) {
            bf16x8 bb = *(const bf16x8*)(Wot + (size_t)(w * 64 + nt * 16 + ln) * 256 + k0 + q * 8);
            acc[nt] = __builtin_amdgcn_mfma_f32_16x16x32_bf16(a, bb, acc[nt], 0, 0, 0);
        }
    }

    float sum[4] = {}, sq[4] = {};
#pragma unroll
    for (int nt = 0; nt < 4; ++nt) {
        const int col = w * 64 + nt * 16 + ln;
        const float bov = bo[col];
#pragma unroll
        for (int r = 0; r < 4; ++r) {
            const int row = r0 + q * 4 + r;
            float v = acc[nt][r] + x[(size_t)row * 256 + col] + bov;
            acc[nt][r] = v;
            sum[r] += v;
            sq[r] += v * v;
        }
    }
#pragma unroll
    for (int r = 0; r < 4; ++r) {
#pragma unroll
        for (int off = 1; off < 16; off <<= 1) {
            sum[r] += __shfl_xor(sum[r], off, 64);
            sq[r]  += __shfl_xor(sq[r],  off, 64);
        }
    }
    if (ln == 0) {
#pragma unroll
        for (int r = 0; r < 4; ++r) {
            redS[q * 4 + r][w] = sum[r];
            redQ[q * 4 + r][w] = sq[r];
        }
    }
    __syncthreads();
#pragma unroll
    for (int nt = 0; nt < 4; ++nt) {
        const int col = w * 64 + nt * 16 + ln;
        const float g = gamma[col], be = beta[col];
#pragma unroll
        for (int r = 0; r < 4; ++r) {
            const int rl = q * 4 + r;
            const float ts = redS[rl][0] + redS[rl][1] + redS[rl][2] + redS[rl][3];
            const float tq = redQ[rl][0] + redQ[rl][1] + redQ[rl][2] + redQ[rl][3];
            const float mu = ts * (1.f / 256.f);
            const float var = tq * (1.f / 256.f) - mu * mu;
            out[(size_t)(r0 + rl) * 256 + col] =
                (acc[nt][r] - mu) * rsqrtf(var + 1e-5f) * g + be;
        }
    }
}

// ---------------------------------------------------------------------------
extern "C" void kernel_launch(void* const* d_in, const int* in_sizes, int n_in,
                              void* d_out, int out_size, void* d_ws, size_t ws_size,
                              hipStream_t stream)
{
    (void)in_sizes; (void)n_in; (void)out_size; (void)ws_size;
    const float* x     = (const float*)d_in[0];
    const float* W1    = (const float*)d_in[1];
    const float* b1    = (const float*)d_in[2];
    const float* w2    = (const float*)d_in[3];
    const float* Wv    = (const float*)d_in[5];
    const float* bv    = (const float*)d_in[6];
    const float* Wo    = (const float*)d_in[7];
    const float* bo    = (const float*)d_in[8];
    const float* gamma = (const float*)d_in[9];
    const float* beta  = (const float*)d_in[10];
    float* out = (float*)d_out;

    // workspace layout in 256KB (64K-float) chunks
    float* ws = (float*)d_ws;
    const size_t CH = 64 * 1024;
    float*  hi      = ws;                       // 8 chunks (2048*256 f32)
    float*  hj      = ws + 8 * CH;              // 8
    float*  sc      = ws + 16 * CH;             // 16 (4*512*512 f32)
    ushort* WAt     = (ushort*)(ws + 32 * CH);  // 1
    ushort* WBt     = (ushort*)(ws + 33 * CH);  // 1
    ushort* Wvt     = (ushort*)(ws + 34 * CH);  // 1
    ushort* Wot     = (ushort*)(ws + 35 * CH);  // 1
    ushort* vals_t  = (ushort*)(ws + 36 * CH);  // 4  (4*256*512 bf16, [b][e][j])
    ushort* attn_bf = (ushort*)(ws + 40 * CH);  // 8  (4*512*512 bf16)
    ushort* msg_bf  = (ushort*)(ws + 48 * CH);  // 4  (2048*256 bf16)

    pack_w       <<<dim3(64),        256, 0, stream>>>(W1, Wv, Wo, WAt, WBt, Wvt, Wot);
    gemm_qkv_mfma<<<dim3(12, 32),    256, 0, stream>>>(x, WAt, WBt, Wvt, b1, bv, hi, hj, vals_t);
    scores64     <<<dim3(16, 8, 4),  256, 0, stream>>>(hi, hj, w2, sc);
    attn_norm    <<<dim3(M),         256, 0, stream>>>(sc, attn_bf);
    pv_mfma      <<<dim3(4, 8, 4),   256, 0, stream>>>(attn_bf, vals_t, msg_bf);
    out_ln_mfma  <<<dim3(128),       256, 0, stream>>>(msg_bf, Wot, x, bo, gamma, beta, out);
}